// Round 10
// baseline (865.052 us; speedup 1.0000x reference)
//
#include <hip/hip_runtime.h>
#include <math.h>

// APPNP: h = relu(x@W1+b1)@W2+b2 ; z_{k+1} = 0.9*Ahat z_k + 0.1*h (10 steps); log_softmax
// Ahat = D^-1/2 (A + I) D^-1/2.
// u-space propagation: u = D^-1/2 z -> (Ahat z)_i = dinv_i * (sum_{j in N(i)} u_j + u_i).
// CSR via bucketed counting sort. MLP via split-bf16 3-term MFMA. u in fp8 e4m3.
// Prop v4: 4 rows per wave (16 lanes each, dword = 4 fp8 features/lane), rows assigned
// in DEGREE-SORTED order (perm) so co-scheduled rows have equal degree (~no waste).
// 8-deep unroll kept (32 edges in flight per wave instruction stream).

constexpr int KSTEPS = 10;

typedef __attribute__((ext_vector_type(8))) short short8;
typedef __attribute__((ext_vector_type(4))) float f32x4;

static __device__ __forceinline__ unsigned short f2bf(float f) {
    unsigned u = __builtin_bit_cast(unsigned, f);
    unsigned r = (u + 0x7FFFu + ((u >> 16) & 1u)) >> 16;
    return (unsigned short)r;
}
static __device__ __forceinline__ float bf2f(unsigned short b) {
    unsigned u = (unsigned)b << 16;
    return __builtin_bit_cast(float, u);
}
static __device__ __forceinline__ void splitbf(float f, short* hi, short* lo) {
    unsigned u = __builtin_bit_cast(unsigned, f);
    *hi = (short)(u >> 16);
    float rem = f - __builtin_bit_cast(float, u & 0xFFFF0000u);
    *lo = (short)f2bf(rem);
}
static __device__ __forceinline__ unsigned char f2fp8(float f) {
    int p = __builtin_amdgcn_cvt_pk_fp8_f32(f, f, 0, false);
    return (unsigned char)(p & 0xFF);
}
// accumulate 4 fp8 lanes of dword v into A (byte-select must be literal)
static __device__ __forceinline__ void acc4(f32x4& A, int v) {
    A[0] += __builtin_amdgcn_cvt_f32_fp8(v, 0);
    A[1] += __builtin_amdgcn_cvt_f32_fp8(v, 1);
    A[2] += __builtin_amdgcn_cvt_f32_fp8(v, 2);
    A[3] += __builtin_amdgcn_cvt_f32_fp8(v, 3);
}

// ---------------- bucketed CSR build ----------------

__global__ void k_zero(int* __restrict__ p, int n) {
    int i = blockIdx.x * 256 + threadIdx.x;
    if (i < n) p[i] = 0;
}

__global__ void k_hist(const int* __restrict__ ei, int* __restrict__ btot, int E, int NB) {
    __shared__ int hist[512];
    for (int t = threadIdx.x; t < NB; t += 256) hist[t] = 0;
    __syncthreads();
    int base = blockIdx.x * 4096;
#pragma unroll
    for (int k = 0; k < 16; ++k) {
        int e = base + k * 256 + threadIdx.x;
        if (e < E) atomicAdd(&hist[ei[e] >> 8], 1);
    }
    __syncthreads();
    for (int t = threadIdx.x; t < NB; t += 256) {
        int c = hist[t];
        if (c) atomicAdd(&btot[t], c);
    }
}

__global__ void k_scanb(const int* __restrict__ btot, int* __restrict__ bstart,
                        int* __restrict__ bcur, int* __restrict__ row_ptr,
                        int NB, int N, int E) {
    __shared__ int lds[512];
    int t = threadIdx.x;
    int v0 = (t < NB) ? btot[t] : 0;
    int v = v0;
    lds[t] = v;
    __syncthreads();
    for (int o = 1; o < 512; o <<= 1) {
        int a = (t >= o) ? lds[t - o] : 0;
        __syncthreads();
        v += a;
        lds[t] = v;
        __syncthreads();
    }
    if (t < NB) {
        int ex = v - v0;
        bstart[t] = ex;
        bcur[t] = ex;
    }
    if (t == 0) {
        bstart[NB] = E;
        row_ptr[N] = E;
    }
}

__launch_bounds__(256)
__global__ void k_part(const int* __restrict__ ei, int* __restrict__ bcur,
                       unsigned* __restrict__ ebuf, int E, int NB) {
    __shared__ int hist[512], rebase[512], lcur[512];
    for (int t = threadIdx.x; t < NB; t += 256) { hist[t] = 0; lcur[t] = 0; }
    __syncthreads();
    int base = blockIdx.x * 4096;
    int r[16], c[16];
#pragma unroll
    for (int k = 0; k < 16; ++k) {
        int e = base + k * 256 + threadIdx.x;
        bool ok = e < E;
        r[k] = ok ? ei[e] : -1;
        c[k] = ok ? ei[E + e] : 0;
        if (ok) atomicAdd(&hist[r[k] >> 8], 1);
    }
    __syncthreads();
    for (int t = threadIdx.x; t < NB; t += 256) {
        int cnt = hist[t];
        rebase[t] = cnt ? atomicAdd(&bcur[t], cnt) : 0;
    }
    __syncthreads();
#pragma unroll
    for (int k = 0; k < 16; ++k) {
        if (r[k] >= 0) {
            int b = r[k] >> 8;
            int pos = rebase[b] + atomicAdd(&lcur[b], 1);
            ebuf[pos] = (unsigned)c[k] | ((unsigned)(r[k] & 255) << 24);
        }
    }
}

__launch_bounds__(256)
__global__ void k_bucket(const unsigned* __restrict__ ebuf, const int* __restrict__ bstart,
                         int* __restrict__ row_ptr, float* __restrict__ dinv,
                         int* __restrict__ cols, int* __restrict__ degarr, int N) {
    __shared__ int cnt[256], cur[256], lds[256];
    int b = blockIdx.x, t = threadIdx.x;
    int s = bstart[b], e2 = bstart[b + 1];
    cnt[t] = 0;
    __syncthreads();
    for (int i = s + t; i < e2; i += 256) {
        unsigned p = ebuf[i];
        atomicAdd(&cnt[p >> 24], 1);
    }
    __syncthreads();
    int v0 = cnt[t];
    int v = v0;
    lds[t] = v;
    __syncthreads();
    for (int o = 1; o < 256; o <<= 1) {
        int a = (t >= o) ? lds[t - o] : 0;
        __syncthreads();
        v += a;
        lds[t] = v;
        __syncthreads();
    }
    int excl = v - v0;
    int row = (b << 8) + t;
    if (row < N) {
        row_ptr[row] = s + excl;
        dinv[row] = rsqrtf((float)(v0 + 1));
        degarr[row] = v0;
    }
    cur[t] = s + excl;
    __syncthreads();
    for (int i = s + t; i < e2; i += 256) {
        unsigned p = ebuf[i];
        int pos = atomicAdd(&cur[p >> 24], 1);
        cols[pos] = (int)(p & 0x00FFFFFFu);
    }
}

// ---------------- degree sort (counting sort, 256 bins) ----------------
__global__ void k_deghist(const int* __restrict__ degarr, int* __restrict__ dbin, int N) {
    __shared__ int h[256];
    h[threadIdx.x] = 0;
    __syncthreads();
    int i = blockIdx.x * 256 + threadIdx.x;
    if (i < N) atomicAdd(&h[min(degarr[i], 255)], 1);
    __syncthreads();
    int c = h[threadIdx.x];
    if (c) atomicAdd(&dbin[threadIdx.x], c);
}

__global__ void k_degscan(int* __restrict__ dbin) {
    __shared__ int lds[256];
    int t = threadIdx.x;
    int v0 = dbin[t];
    int v = v0;
    lds[t] = v;
    __syncthreads();
    for (int o = 1; o < 256; o <<= 1) {
        int a = (t >= o) ? lds[t - o] : 0;
        __syncthreads();
        v += a;
        lds[t] = v;
        __syncthreads();
    }
    dbin[t] = v - v0;
}

__global__ void k_degscatter(const int* __restrict__ degarr, int* __restrict__ dbin,
                             int* __restrict__ perm, int N) {
    int i = blockIdx.x * 256 + threadIdx.x;
    if (i < N) {
        int d = min(degarr[i], 255);
        int pos = atomicAdd(&dbin[d], 1);
        perm[pos] = i;
    }
}

// zero-pad row N of the u buffers (predicated tail gathers land here)
__global__ void k_zrow(unsigned char* __restrict__ a, unsigned char* __restrict__ b,
                       unsigned char* __restrict__ c, int N) {
    int t = threadIdx.x;  // 64
    size_t o = (size_t)N * 64 + t;
    a[o] = 0; b[o] = 0; c[o] = 0;
}

// ---------------- weight packing (hi/lo split) ----------------
__global__ void k_pack_w1(const float* __restrict__ w1, short* __restrict__ w1fh,
                          short* __restrict__ w1fl) {
    int t = blockIdx.x * 256 + threadIdx.x;  // 65536 total
    int j = t & 7, lane = (t >> 3) & 63, nb = (t >> 9) & 3, kb = t >> 11;
    int k = kb * 32 + ((lane >> 4) << 3) + j;
    int c = nb * 16 + (lane & 15);
    short hi, lo;
    splitbf(w1[k * 64 + c], &hi, &lo);
    w1fh[t] = hi;
    w1fl[t] = lo;
}

__global__ void k_pack_w2(const float* __restrict__ w2, short* __restrict__ w2fh,
                          short* __restrict__ w2fl) {
    int t = blockIdx.x * 256 + threadIdx.x;  // 4096 total
    int j = t & 7, lane = (t >> 3) & 63, nb = (t >> 9) & 3, kb = (t >> 11) & 1;
    int k = kb * 32 + ((lane >> 4) << 3) + j;
    int c = nb * 16 + (lane & 15);
    short hi, lo;
    splitbf(w2[k * 64 + c], &hi, &lo);
    w2fh[t] = hi;
    w2fl[t] = lo;
}

// ---------------- fused 2-layer MLP via split-bf16 MFMA (3-term) ----------------
__launch_bounds__(256)
__global__ void k_mlp(const float* __restrict__ x,
                      const short8* __restrict__ w1fh, const short8* __restrict__ w1fl,
                      const float* __restrict__ b1,
                      const short8* __restrict__ w2fh, const short8* __restrict__ w2fl,
                      const float* __restrict__ b2, const float* __restrict__ dinv,
                      unsigned short* __restrict__ ah, unsigned char* __restrict__ u0,
                      int M, int F) {
    __shared__ __align__(16) short c1sh[4][16][64];
    __shared__ __align__(16) short c1sl[4][16][64];
    int tid = threadIdx.x;
    int w = tid >> 6, lane = tid & 63;
    int hi = lane >> 4, lx = lane & 15;
    int rbase = blockIdx.x * 64 + w * 16;
    int row = rbase + lx;
    size_t rowc = (row < M) ? (size_t)row : (size_t)(M - 1);
    const float* xr = x + rowc * (size_t)F + hi * 8;

    f32x4 acc[4];
#pragma unroll
    for (int nb = 0; nb < 4; ++nb) acc[nb] = (f32x4){0.f, 0.f, 0.f, 0.f};

    int KK = F >> 5;
#pragma unroll 2
    for (int kk = 0; kk < KK; ++kk) {
        float4 a0 = *reinterpret_cast<const float4*>(xr + kk * 32);
        float4 a1 = *reinterpret_cast<const float4*>(xr + kk * 32 + 4);
        float av[8] = {a0.x, a0.y, a0.z, a0.w, a1.x, a1.y, a1.z, a1.w};
        short8 afh, afl;
#pragma unroll
        for (int j = 0; j < 8; ++j) {
            short h8, l8;
            splitbf(av[j], &h8, &l8);
            afh[j] = h8;
            afl[j] = l8;
        }
#pragma unroll
        for (int nb = 0; nb < 4; ++nb) {
            short8 bfh = w1fh[(kk * 4 + nb) * 64 + lane];
            short8 bfl = w1fl[(kk * 4 + nb) * 64 + lane];
            acc[nb] = __builtin_amdgcn_mfma_f32_16x16x32_bf16(afh, bfh, acc[nb], 0, 0, 0);
            acc[nb] = __builtin_amdgcn_mfma_f32_16x16x32_bf16(afl, bfh, acc[nb], 0, 0, 0);
            acc[nb] = __builtin_amdgcn_mfma_f32_16x16x32_bf16(afh, bfl, acc[nb], 0, 0, 0);
        }
    }

    short* myh = &c1sh[w][0][0];
    short* myl = &c1sl[w][0][0];
#pragma unroll
    for (int nb = 0; nb < 4; ++nb) {
        int col = nb * 16 + lx;
        float bb = b1[col];
#pragma unroll
        for (int r = 0; r < 4; ++r) {
            int rr = hi * 4 + r;
            float v = fmaxf(acc[nb][r] + bb, 0.f);
            short h8, l8;
            splitbf(v, &h8, &l8);
            myh[rr * 64 + col] = h8;
            myl[rr * 64 + col] = l8;
        }
    }
    __syncthreads();

    f32x4 acc2[4];
#pragma unroll
    for (int nb = 0; nb < 4; ++nb) acc2[nb] = (f32x4){0.f, 0.f, 0.f, 0.f};
#pragma unroll
    for (int kb = 0; kb < 2; ++kb) {
        short8 a2h = *reinterpret_cast<const short8*>(&myh[lx * 64 + kb * 32 + hi * 8]);
        short8 a2l = *reinterpret_cast<const short8*>(&myl[lx * 64 + kb * 32 + hi * 8]);
#pragma unroll
        for (int nb = 0; nb < 4; ++nb) {
            short8 bfh = w2fh[(kb * 4 + nb) * 64 + lane];
            short8 bfl = w2fl[(kb * 4 + nb) * 64 + lane];
            acc2[nb] = __builtin_amdgcn_mfma_f32_16x16x32_bf16(a2h, bfh, acc2[nb], 0, 0, 0);
            acc2[nb] = __builtin_amdgcn_mfma_f32_16x16x32_bf16(a2l, bfh, acc2[nb], 0, 0, 0);
            acc2[nb] = __builtin_amdgcn_mfma_f32_16x16x32_bf16(a2h, bfl, acc2[nb], 0, 0, 0);
        }
    }

#pragma unroll
    for (int r = 0; r < 4; ++r) {
        int orow = rbase + hi * 4 + r;
        float dv = (orow < M) ? dinv[orow] : 0.f;
#pragma unroll
        for (int nb = 0; nb < 4; ++nb) {
            int col = nb * 16 + lx;
            if (orow < M) {
                float v = acc2[nb][r] + b2[col];
                ah[(size_t)orow * 64 + col] = f2bf(0.1f * v);
                u0[(size_t)orow * 64 + col] = f2fp8(dv * v);
            }
        }
    }
}

// ---------------- propagation v4: 4 degree-matched rows per wave ----------------
// wave handles rows perm[slot..slot+3]; group g = lane>>4 owns one row; fl = lane&15
// owns features 4fl..4fl+3 (one dword of fp8). 8-deep unroll = 8 gathers in flight.
__global__ void k_prop(const unsigned char* __restrict__ uin, const unsigned short* __restrict__ ah,
                       const float* __restrict__ dinv, const int* __restrict__ row_ptr,
                       const int* __restrict__ cols, const int* __restrict__ perm,
                       unsigned char* __restrict__ uout, int n, int E) {
    int wid = threadIdx.x >> 6;
    int lane = threadIdx.x & 63;
    int g = lane >> 4, fl = lane & 15;
    int slot = blockIdx.x * 16 + wid * 4 + g;
    int r = perm[min(slot, n - 1)];
    int e0 = row_ptr[r], end_ = row_ptr[r + 1];
    int trips = (end_ - e0 + 7) >> 3;
    const unsigned char* up = uin + fl * 4;

    f32x4 A0 = {0.f, 0.f, 0.f, 0.f}, A1 = A0, A2 = A0, A3 = A0;
    f32x4 A4 = A0, A5 = A0, A6 = A0, A7 = A0;
    for (int t = 0; t < trips; ++t) {
        int base = e0 + t * 8;
        int c0 = (base     < end_) ? cols[min(base,     E - 1)] : n;
        int c1 = (base + 1 < end_) ? cols[min(base + 1, E - 1)] : n;
        int c2 = (base + 2 < end_) ? cols[min(base + 2, E - 1)] : n;
        int c3 = (base + 3 < end_) ? cols[min(base + 3, E - 1)] : n;
        int c4 = (base + 4 < end_) ? cols[min(base + 4, E - 1)] : n;
        int c5 = (base + 5 < end_) ? cols[min(base + 5, E - 1)] : n;
        int c6 = (base + 6 < end_) ? cols[min(base + 6, E - 1)] : n;
        int c7 = (base + 7 < end_) ? cols[min(base + 7, E - 1)] : n;
        int v0 = *reinterpret_cast<const int*>(up + (size_t)c0 * 64);
        int v1 = *reinterpret_cast<const int*>(up + (size_t)c1 * 64);
        int v2 = *reinterpret_cast<const int*>(up + (size_t)c2 * 64);
        int v3 = *reinterpret_cast<const int*>(up + (size_t)c3 * 64);
        int v4 = *reinterpret_cast<const int*>(up + (size_t)c4 * 64);
        int v5 = *reinterpret_cast<const int*>(up + (size_t)c5 * 64);
        int v6 = *reinterpret_cast<const int*>(up + (size_t)c6 * 64);
        int v7 = *reinterpret_cast<const int*>(up + (size_t)c7 * 64);
        acc4(A0, v0); acc4(A1, v1); acc4(A2, v2); acc4(A3, v3);
        acc4(A4, v4); acc4(A5, v5); acc4(A6, v6); acc4(A7, v7);
    }
    int sv = *reinterpret_cast<const int*>(uin + (size_t)r * 64 + fl * 4);
    uint2 av = *reinterpret_cast<const uint2*>(ah + (size_t)r * 64 + fl * 4);
    float di = dinv[r];
    float w = 0.9f * di;
    float z0 = fmaf(w, ((A0[0] + A1[0]) + (A2[0] + A3[0])) + ((A4[0] + A5[0]) + (A6[0] + A7[0]))
                       + __builtin_amdgcn_cvt_f32_fp8(sv, 0),
                    bf2f((unsigned short)(av.x & 0xFFFF)));
    float z1 = fmaf(w, ((A0[1] + A1[1]) + (A2[1] + A3[1])) + ((A4[1] + A5[1]) + (A6[1] + A7[1]))
                       + __builtin_amdgcn_cvt_f32_fp8(sv, 1),
                    bf2f((unsigned short)(av.x >> 16)));
    float z2 = fmaf(w, ((A0[2] + A1[2]) + (A2[2] + A3[2])) + ((A4[2] + A5[2]) + (A6[2] + A7[2]))
                       + __builtin_amdgcn_cvt_f32_fp8(sv, 2),
                    bf2f((unsigned short)(av.y & 0xFFFF)));
    float z3 = fmaf(w, ((A0[3] + A1[3]) + (A2[3] + A3[3])) + ((A4[3] + A5[3]) + (A6[3] + A7[3]))
                       + __builtin_amdgcn_cvt_f32_fp8(sv, 3),
                    bf2f((unsigned short)(av.y >> 16)));
    if (slot < n) {
        int o = __builtin_amdgcn_cvt_pk_fp8_f32(di * z0, di * z1, 0, false);
        o = __builtin_amdgcn_cvt_pk_fp8_f32(di * z2, di * z3, o, true);
        *reinterpret_cast<int*>(uout + (size_t)r * 64 + fl * 4) = o;
    }
}

// final step fused with log_softmax, writes f32 out
__global__ void k_prop_lsm(const unsigned char* __restrict__ uin, const unsigned short* __restrict__ ah,
                           const float* __restrict__ dinv, const int* __restrict__ row_ptr,
                           const int* __restrict__ cols, const int* __restrict__ perm,
                           float* __restrict__ out, int n, int E) {
    int wid = threadIdx.x >> 6;
    int lane = threadIdx.x & 63;
    int g = lane >> 4, fl = lane & 15;
    int slot = blockIdx.x * 16 + wid * 4 + g;
    int r = perm[min(slot, n - 1)];
    int e0 = row_ptr[r], end_ = row_ptr[r + 1];
    int trips = (end_ - e0 + 7) >> 3;
    const unsigned char* up = uin + fl * 4;

    f32x4 A0 = {0.f, 0.f, 0.f, 0.f}, A1 = A0, A2 = A0, A3 = A0;
    f32x4 A4 = A0, A5 = A0, A6 = A0, A7 = A0;
    for (int t = 0; t < trips; ++t) {
        int base = e0 + t * 8;
        int c0 = (base     < end_) ? cols[min(base,     E - 1)] : n;
        int c1 = (base + 1 < end_) ? cols[min(base + 1, E - 1)] : n;
        int c2 = (base + 2 < end_) ? cols[min(base + 2, E - 1)] : n;
        int c3 = (base + 3 < end_) ? cols[min(base + 3, E - 1)] : n;
        int c4 = (base + 4 < end_) ? cols[min(base + 4, E - 1)] : n;
        int c5 = (base + 5 < end_) ? cols[min(base + 5, E - 1)] : n;
        int c6 = (base + 6 < end_) ? cols[min(base + 6, E - 1)] : n;
        int c7 = (base + 7 < end_) ? cols[min(base + 7, E - 1)] : n;
        int v0 = *reinterpret_cast<const int*>(up + (size_t)c0 * 64);
        int v1 = *reinterpret_cast<const int*>(up + (size_t)c1 * 64);
        int v2 = *reinterpret_cast<const int*>(up + (size_t)c2 * 64);
        int v3 = *reinterpret_cast<const int*>(up + (size_t)c3 * 64);
        int v4 = *reinterpret_cast<const int*>(up + (size_t)c4 * 64);
        int v5 = *reinterpret_cast<const int*>(up + (size_t)c5 * 64);
        int v6 = *reinterpret_cast<const int*>(up + (size_t)c6 * 64);
        int v7 = *reinterpret_cast<const int*>(up + (size_t)c7 * 64);
        acc4(A0, v0); acc4(A1, v1); acc4(A2, v2); acc4(A3, v3);
        acc4(A4, v4); acc4(A5, v5); acc4(A6, v6); acc4(A7, v7);
    }
    int sv = *reinterpret_cast<const int*>(uin + (size_t)r * 64 + fl * 4);
    uint2 av = *reinterpret_cast<const uint2*>(ah + (size_t)r * 64 + fl * 4);
    float di = dinv[r];
    float w = 0.9f * di;
    float z0 = fmaf(w, ((A0[0] + A1[0]) + (A2[0] + A3[0])) + ((A4[0] + A5[0]) + (A6[0] + A7[0]))
                       + __builtin_amdgcn_cvt_f32_fp8(sv, 0),
                    bf2f((unsigned short)(av.x & 0xFFFF)));
    float z1 = fmaf(w, ((A0[1] + A1[1]) + (A2[1] + A3[1])) + ((A4[1] + A5[1]) + (A6[1] + A7[1]))
                       + __builtin_amdgcn_cvt_f32_fp8(sv, 1),
                    bf2f((unsigned short)(av.x >> 16)));
    float z2 = fmaf(w, ((A0[2] + A1[2]) + (A2[2] + A3[2])) + ((A4[2] + A5[2]) + (A6[2] + A7[2]))
                       + __builtin_amdgcn_cvt_f32_fp8(sv, 2),
                    bf2f((unsigned short)(av.y & 0xFFFF)));
    float z3 = fmaf(w, ((A0[3] + A1[3]) + (A2[3] + A3[3])) + ((A4[3] + A5[3]) + (A6[3] + A7[3]))
                       + __builtin_amdgcn_cvt_f32_fp8(sv, 3),
                    bf2f((unsigned short)(av.y >> 16)));
    // softmax across the 16 feature-lanes of this group (xor offsets 1..8 stay in-group)
    float m = fmaxf(fmaxf(z0, z1), fmaxf(z2, z3));
#pragma unroll
    for (int o = 1; o <= 8; o <<= 1) m = fmaxf(m, __shfl_xor(m, o, 64));
    float s = expf(z0 - m) + expf(z1 - m) + expf(z2 - m) + expf(z3 - m);
#pragma unroll
    for (int o = 1; o <= 8; o <<= 1) s += __shfl_xor(s, o, 64);
    float ls = m + logf(s);
    if (slot < n) {
        float4 o4 = make_float4(z0 - ls, z1 - ls, z2 - ls, z3 - ls);
        *reinterpret_cast<float4*>(out + (size_t)r * 64 + fl * 4) = o4;
    }
}

// ---------------- launch ----------------
extern "C" void kernel_launch(void* const* d_in, const int* in_sizes, int n_in,
                              void* d_out, int out_size, void* d_ws, size_t ws_size,
                              hipStream_t stream) {
    const float* x  = (const float*)d_in[0];
    const float* w1 = (const float*)d_in[1];
    const float* b1 = (const float*)d_in[2];
    const float* w2 = (const float*)d_in[3];
    const float* b2 = (const float*)d_in[4];
    const int*   ei = (const int*)d_in[5];
    // d_in[6] = K (always 10; launch count must be graph-static)

    int F = in_sizes[1] / 64;         // 1024
    int N = in_sizes[0] / F;          // 100000
    int E = in_sizes[5] / 2;          // 3200000
    int NB = (N + 255) >> 8;          // 391 buckets

    char* p = (char*)d_ws;
    auto alloc = [&](size_t bytes) {
        void* r = (void*)p;
        p += (bytes + 255) & ~(size_t)255;
        return r;
    };
    unsigned short* ah   = (unsigned short*)alloc((size_t)N * 64 * 2);
    unsigned char*  u0   = (unsigned char*)alloc((size_t)(N + 1) * 64);
    unsigned char*  uA   = (unsigned char*)alloc((size_t)(N + 1) * 64);
    unsigned char*  uB   = (unsigned char*)alloc((size_t)(N + 1) * 64);
    float* dinv    = (float*)alloc((size_t)N * 4);
    int*   row_ptr = (int*)alloc((size_t)(N + 1) * 4);
    int*   btot    = (int*)alloc(2048);
    int*   bstart  = (int*)alloc(2048);
    int*   bcur    = (int*)alloc(2048);
    int*   dbin    = (int*)alloc(1024);
    int*   degarr  = (int*)alloc((size_t)N * 4);
    int*   perm    = (int*)alloc((size_t)N * 4);
    unsigned* ebuf = (unsigned*)alloc((size_t)E * 4);
    int*   cols    = (int*)alloc((size_t)E * 4);
    short* w1fh    = (short*)alloc((size_t)F * 64 * 2);
    short* w1fl    = (short*)alloc((size_t)F * 64 * 2);
    short* w2fh    = (short*)alloc((size_t)64 * 64 * 2);
    short* w2fl    = (short*)alloc((size_t)64 * 64 * 2);

    int neb = (E + 4095) / 4096;
    int nnb = (N + 255) / 256;

    k_zero<<<2, 256, 0, stream>>>(btot, NB);
    k_zero<<<1, 256, 0, stream>>>(dbin, 256);
    k_hist<<<neb, 256, 0, stream>>>(ei, btot, E, NB);
    k_scanb<<<1, 512, 0, stream>>>(btot, bstart, bcur, row_ptr, NB, N, E);
    k_part<<<neb, 256, 0, stream>>>(ei, bcur, ebuf, E, NB);
    k_bucket<<<NB, 256, 0, stream>>>(ebuf, bstart, row_ptr, dinv, cols, degarr, N);
    k_deghist<<<nnb, 256, 0, stream>>>(degarr, dbin, N);
    k_degscan<<<1, 256, 0, stream>>>(dbin);
    k_degscatter<<<nnb, 256, 0, stream>>>(degarr, dbin, perm, N);
    k_zrow<<<1, 64, 0, stream>>>(u0, uA, uB, N);
    k_pack_w1<<<(F * 64) / 256, 256, 0, stream>>>(w1, w1fh, w1fl);
    k_pack_w2<<<16, 256, 0, stream>>>(w2, w2fh, w2fl);
    k_mlp<<<(N + 63) / 64, 256, 0, stream>>>(x, (const short8*)w1fh, (const short8*)w1fl, b1,
                                             (const short8*)w2fh, (const short8*)w2fl, b2,
                                             dinv, ah, u0, N, F);

    const unsigned char* uin = u0;
    unsigned char* bufs[2] = {uA, uB};
    int npb = (N + 15) / 16;  // 16 rows per block (4 waves x 4 rows)
    for (int k = 0; k < KSTEPS - 1; ++k) {
        unsigned char* uo = bufs[k & 1];
        k_prop<<<npb, 256, 0, stream>>>(uin, ah, dinv, row_ptr, cols, perm, uo, N, E);
        uin = uo;
    }
    k_prop_lsm<<<npb, 256, 0, stream>>>(uin, ah, dinv, row_ptr, cols, perm, (float*)d_out, N, E);
}

// Round 11
// 678.622 us; speedup vs baseline: 1.2747x; 1.2747x over previous
//
#include <hip/hip_runtime.h>
#include <math.h>

// APPNP: h = relu(x@W1+b1)@W2+b2 ; z_{k+1} = 0.9*Ahat z_k + 0.1*h (10 steps); log_softmax
// Ahat = D^-1/2 (A + I) D^-1/2.
// u-space propagation: u = D^-1/2 z -> (Ahat z)_i = dinv_i * (sum_{j in N(i)} u_j + u_i).
// CSR via bucketed counting sort. MLP via plain bf16 MFMA (absmax ledger: split-bf16
// never moved max error; plain halves L2 w-traffic). u in fp8 e4m3; ah=0.1*h bf16.
// Prop v3 (best measured): two adjacent rows per wave, 32 lanes each (2 fp8 feats/lane),
// 8-deep unroll; cols padded so inner loads are unconditional (compiler merges to dwordx4).

constexpr int KSTEPS = 10;

typedef __attribute__((ext_vector_type(8))) short short8;
typedef __attribute__((ext_vector_type(4))) float f32x4;

static __device__ __forceinline__ unsigned short f2bf(float f) {
    unsigned u = __builtin_bit_cast(unsigned, f);
    unsigned r = (u + 0x7FFFu + ((u >> 16) & 1u)) >> 16;
    return (unsigned short)r;
}
static __device__ __forceinline__ float bf2f(unsigned short b) {
    unsigned u = (unsigned)b << 16;
    return __builtin_bit_cast(float, u);
}
static __device__ __forceinline__ unsigned char f2fp8(float f) {
    int p = __builtin_amdgcn_cvt_pk_fp8_f32(f, f, 0, false);
    return (unsigned char)(p & 0xFF);
}
// fp8 byte-selects on a zero-extended ushort (bytes 0,1)
static __device__ __forceinline__ float fp8b0(unsigned v) {
    return __builtin_amdgcn_cvt_f32_fp8((int)v, 0);
}
static __device__ __forceinline__ float fp8b1(unsigned v) {
    return __builtin_amdgcn_cvt_f32_fp8((int)v, 1);
}

// ---------------- bucketed CSR build ----------------
// bucket = row >> 8 (256 rows per bucket); NB = ceil(N/256) buckets

__global__ void k_zero(int* __restrict__ p, int n) {
    int i = blockIdx.x * 256 + threadIdx.x;
    if (i < n) p[i] = 0;
}

__global__ void k_hist(const int* __restrict__ ei, int* __restrict__ btot, int E, int NB) {
    __shared__ int hist[512];
    for (int t = threadIdx.x; t < NB; t += 256) hist[t] = 0;
    __syncthreads();
    int base = blockIdx.x * 4096;
#pragma unroll
    for (int k = 0; k < 16; ++k) {
        int e = base + k * 256 + threadIdx.x;
        if (e < E) atomicAdd(&hist[ei[e] >> 8], 1);
    }
    __syncthreads();
    for (int t = threadIdx.x; t < NB; t += 256) {
        int c = hist[t];
        if (c) atomicAdd(&btot[t], c);
    }
}

__global__ void k_scanb(const int* __restrict__ btot, int* __restrict__ bstart,
                        int* __restrict__ bcur, int* __restrict__ row_ptr,
                        int NB, int N, int E) {
    __shared__ int lds[512];
    int t = threadIdx.x;
    int v0 = (t < NB) ? btot[t] : 0;
    int v = v0;
    lds[t] = v;
    __syncthreads();
    for (int o = 1; o < 512; o <<= 1) {
        int a = (t >= o) ? lds[t - o] : 0;
        __syncthreads();
        v += a;
        lds[t] = v;
        __syncthreads();
    }
    if (t < NB) {
        int ex = v - v0;
        bstart[t] = ex;
        bcur[t] = ex;
    }
    if (t == 0) {
        bstart[NB] = E;
        row_ptr[N] = E;
    }
}

// partition edges into bucket slices; entry packed as col | (row&255)<<24 (col < 2^17)
__launch_bounds__(256)
__global__ void k_part(const int* __restrict__ ei, int* __restrict__ bcur,
                       unsigned* __restrict__ ebuf, int E, int NB) {
    __shared__ int hist[512], rebase[512], lcur[512];
    for (int t = threadIdx.x; t < NB; t += 256) { hist[t] = 0; lcur[t] = 0; }
    __syncthreads();
    int base = blockIdx.x * 4096;
    int r[16], c[16];
#pragma unroll
    for (int k = 0; k < 16; ++k) {
        int e = base + k * 256 + threadIdx.x;
        bool ok = e < E;
        r[k] = ok ? ei[e] : -1;
        c[k] = ok ? ei[E + e] : 0;
        if (ok) atomicAdd(&hist[r[k] >> 8], 1);
    }
    __syncthreads();
    for (int t = threadIdx.x; t < NB; t += 256) {
        int cnt = hist[t];
        rebase[t] = cnt ? atomicAdd(&bcur[t], cnt) : 0;
    }
    __syncthreads();
#pragma unroll
    for (int k = 0; k < 16; ++k) {
        if (r[k] >= 0) {
            int b = r[k] >> 8;
            int pos = rebase[b] + atomicAdd(&lcur[b], 1);
            ebuf[pos] = (unsigned)c[k] | ((unsigned)(r[k] & 255) << 24);
        }
    }
}

__launch_bounds__(256)
__global__ void k_bucket(const unsigned* __restrict__ ebuf, const int* __restrict__ bstart,
                         int* __restrict__ row_ptr, float* __restrict__ dinv,
                         int* __restrict__ cols, int N) {
    __shared__ int cnt[256], cur[256], lds[256];
    int b = blockIdx.x, t = threadIdx.x;
    int s = bstart[b], e2 = bstart[b + 1];
    cnt[t] = 0;
    __syncthreads();
    for (int i = s + t; i < e2; i += 256) {
        unsigned p = ebuf[i];
        atomicAdd(&cnt[p >> 24], 1);
    }
    __syncthreads();
    int v0 = cnt[t];
    int v = v0;
    lds[t] = v;
    __syncthreads();
    for (int o = 1; o < 256; o <<= 1) {
        int a = (t >= o) ? lds[t - o] : 0;
        __syncthreads();
        v += a;
        lds[t] = v;
        __syncthreads();
    }
    int excl = v - v0;
    int row = (b << 8) + t;
    if (row < N) {
        row_ptr[row] = s + excl;
        dinv[row] = rsqrtf((float)(v0 + 1));
    }
    cur[t] = s + excl;
    __syncthreads();
    for (int i = s + t; i < e2; i += 256) {
        unsigned p = ebuf[i];
        int pos = atomicAdd(&cur[p >> 24], 1);
        cols[pos] = (int)(p & 0x00FFFFFFu);
    }
}

// zero-pad row N of the u buffers (predicated tail gathers land here)
__global__ void k_zrow(unsigned char* __restrict__ a, unsigned char* __restrict__ b,
                       unsigned char* __restrict__ c, int N) {
    int t = threadIdx.x;  // 64
    size_t o = (size_t)N * 64 + t;
    a[o] = 0; b[o] = 0; c[o] = 0;
}

// ---------------- weight packing into MFMA fragment order ----------------
__global__ void k_pack_w1(const float* __restrict__ w1, short* __restrict__ w1f) {
    int t = blockIdx.x * 256 + threadIdx.x;  // 65536 total
    int j = t & 7, lane = (t >> 3) & 63, nb = (t >> 9) & 3, kb = t >> 11;
    int k = kb * 32 + ((lane >> 4) << 3) + j;
    int c = nb * 16 + (lane & 15);
    w1f[t] = (short)f2bf(w1[k * 64 + c]);
}

__global__ void k_pack_w2(const float* __restrict__ w2, short* __restrict__ w2f) {
    int t = blockIdx.x * 256 + threadIdx.x;  // 4096 total
    int j = t & 7, lane = (t >> 3) & 63, nb = (t >> 9) & 3, kb = (t >> 11) & 1;
    int k = kb * 32 + ((lane >> 4) << 3) + j;
    int c = nb * 16 + (lane & 15);
    w2f[t] = (short)f2bf(w2[k * 64 + c]);
}

// ---------------- fused 2-layer MLP via bf16 MFMA ----------------
// writes ah = bf16(0.1*h) (teleport term) and u0 = fp8(dinv*h) (propagation state)
__launch_bounds__(256)
__global__ void k_mlp(const float* __restrict__ x, const short8* __restrict__ w1f,
                      const float* __restrict__ b1, const short8* __restrict__ w2f,
                      const float* __restrict__ b2, const float* __restrict__ dinv,
                      unsigned short* __restrict__ ah, unsigned char* __restrict__ u0,
                      int M, int F) {
    __shared__ __align__(16) short c1s[4][16][64];
    int tid = threadIdx.x;
    int w = tid >> 6, lane = tid & 63;
    int hi = lane >> 4, lx = lane & 15;
    int rbase = blockIdx.x * 64 + w * 16;
    int row = rbase + lx;
    size_t rowc = (row < M) ? (size_t)row : (size_t)(M - 1);
    const float* xr = x + rowc * (size_t)F + hi * 8;

    f32x4 acc[4];
#pragma unroll
    for (int nb = 0; nb < 4; ++nb) acc[nb] = (f32x4){0.f, 0.f, 0.f, 0.f};

    int KK = F >> 5;
#pragma unroll 4
    for (int kk = 0; kk < KK; ++kk) {
        float4 a0 = *reinterpret_cast<const float4*>(xr + kk * 32);
        float4 a1 = *reinterpret_cast<const float4*>(xr + kk * 32 + 4);
        short8 af;
        af[0] = (short)f2bf(a0.x); af[1] = (short)f2bf(a0.y);
        af[2] = (short)f2bf(a0.z); af[3] = (short)f2bf(a0.w);
        af[4] = (short)f2bf(a1.x); af[5] = (short)f2bf(a1.y);
        af[6] = (short)f2bf(a1.z); af[7] = (short)f2bf(a1.w);
#pragma unroll
        for (int nb = 0; nb < 4; ++nb) {
            short8 bf = w1f[(kk * 4 + nb) * 64 + lane];
            acc[nb] = __builtin_amdgcn_mfma_f32_16x16x32_bf16(af, bf, acc[nb], 0, 0, 0);
        }
    }

    short* my = &c1s[w][0][0];
#pragma unroll
    for (int nb = 0; nb < 4; ++nb) {
        int col = nb * 16 + lx;
        float bb = b1[col];
#pragma unroll
        for (int r = 0; r < 4; ++r) {
            int rr = hi * 4 + r;
            my[rr * 64 + col] = (short)f2bf(fmaxf(acc[nb][r] + bb, 0.f));
        }
    }
    __syncthreads();

    f32x4 acc2[4];
#pragma unroll
    for (int nb = 0; nb < 4; ++nb) acc2[nb] = (f32x4){0.f, 0.f, 0.f, 0.f};
#pragma unroll
    for (int kb = 0; kb < 2; ++kb) {
        short8 af2 = *reinterpret_cast<const short8*>(&my[lx * 64 + kb * 32 + hi * 8]);
#pragma unroll
        for (int nb = 0; nb < 4; ++nb) {
            short8 bf2 = w2f[(kb * 4 + nb) * 64 + lane];
            acc2[nb] = __builtin_amdgcn_mfma_f32_16x16x32_bf16(af2, bf2, acc2[nb], 0, 0, 0);
        }
    }

#pragma unroll
    for (int r = 0; r < 4; ++r) {
        int orow = rbase + hi * 4 + r;
        float dv = (orow < M) ? dinv[orow] : 0.f;
#pragma unroll
        for (int nb = 0; nb < 4; ++nb) {
            int col = nb * 16 + lx;
            if (orow < M) {
                float v = acc2[nb][r] + b2[col];
                ah[(size_t)orow * 64 + col] = f2bf(0.1f * v);
                u0[(size_t)orow * 64 + col] = f2fp8(dv * v);
            }
        }
    }
}

// ---------------- propagation v3: 2 adjacent rows per wave (fp8 u) ----------------
// wave w handles rows (2w, 2w+1); half = lane>>5 selects row; fl = lane&31 owns
// features 2fl, 2fl+1. cols padded -> unconditional consecutive loads (merge to dwordx4).
__global__ void k_prop(const unsigned char* __restrict__ uin, const unsigned short* __restrict__ ah,
                       const float* __restrict__ dinv, const int* __restrict__ row_ptr,
                       const int* __restrict__ cols, unsigned char* __restrict__ uout, int n) {
    int wid = threadIdx.x >> 6;
    int lane = threadIdx.x & 63;
    int half = lane >> 5, fl = lane & 31;
    int r0 = blockIdx.x * 8 + wid * 2;
    int ra = min(r0, n - 1), rb = min(r0 + 1, n - 1);
    int ea = row_ptr[ra], enda = row_ptr[ra + 1];
    int eb = row_ptr[rb], endb = row_ptr[rb + 1];
    int trips = (max(enda - ea, endb - eb) + 7) >> 3;
    int e0 = half ? eb : ea;
    int end_ = half ? endb : enda;
    int r = half ? rb : ra;

    float s0 = 0.f, s1 = 0.f, s2 = 0.f, s3 = 0.f, s4 = 0.f, s5 = 0.f, s6 = 0.f, s7 = 0.f;
    float t0 = 0.f, t1 = 0.f, t2 = 0.f, t3 = 0.f, t4 = 0.f, t5 = 0.f, t6 = 0.f, t7 = 0.f;
    for (int t = 0; t < trips; ++t) {
        int base = e0 + t * 8;
        int q0 = cols[base],     q1 = cols[base + 1], q2 = cols[base + 2], q3 = cols[base + 3];
        int q4 = cols[base + 4], q5 = cols[base + 5], q6 = cols[base + 6], q7 = cols[base + 7];
        int c0 = (base     < end_) ? q0 : n;
        int c1 = (base + 1 < end_) ? q1 : n;
        int c2 = (base + 2 < end_) ? q2 : n;
        int c3 = (base + 3 < end_) ? q3 : n;
        int c4 = (base + 4 < end_) ? q4 : n;
        int c5 = (base + 5 < end_) ? q5 : n;
        int c6 = (base + 6 < end_) ? q6 : n;
        int c7 = (base + 7 < end_) ? q7 : n;
        unsigned v0 = *reinterpret_cast<const unsigned short*>(uin + (size_t)c0 * 64 + fl * 2);
        unsigned v1 = *reinterpret_cast<const unsigned short*>(uin + (size_t)c1 * 64 + fl * 2);
        unsigned v2 = *reinterpret_cast<const unsigned short*>(uin + (size_t)c2 * 64 + fl * 2);
        unsigned v3 = *reinterpret_cast<const unsigned short*>(uin + (size_t)c3 * 64 + fl * 2);
        unsigned v4 = *reinterpret_cast<const unsigned short*>(uin + (size_t)c4 * 64 + fl * 2);
        unsigned v5 = *reinterpret_cast<const unsigned short*>(uin + (size_t)c5 * 64 + fl * 2);
        unsigned v6 = *reinterpret_cast<const unsigned short*>(uin + (size_t)c6 * 64 + fl * 2);
        unsigned v7 = *reinterpret_cast<const unsigned short*>(uin + (size_t)c7 * 64 + fl * 2);
        s0 += fp8b0(v0); t0 += fp8b1(v0);
        s1 += fp8b0(v1); t1 += fp8b1(v1);
        s2 += fp8b0(v2); t2 += fp8b1(v2);
        s3 += fp8b0(v3); t3 += fp8b1(v3);
        s4 += fp8b0(v4); t4 += fp8b1(v4);
        s5 += fp8b0(v5); t5 += fp8b1(v5);
        s6 += fp8b0(v6); t6 += fp8b1(v6);
        s7 += fp8b0(v7); t7 += fp8b1(v7);
    }
    float sa = ((s0 + s1) + (s2 + s3)) + ((s4 + s5) + (s6 + s7));
    float sb = ((t0 + t1) + (t2 + t3)) + ((t4 + t5) + (t6 + t7));
    unsigned sv = *reinterpret_cast<const unsigned short*>(uin + (size_t)r * 64 + fl * 2);
    unsigned av = *reinterpret_cast<const unsigned*>(ah + (size_t)r * 64 + fl * 2);
    float di = dinv[r];
    float w = 0.9f * di;
    float z0 = fmaf(w, sa + fp8b0(sv), bf2f((unsigned short)(av & 0xFFFF)));
    float z1 = fmaf(w, sb + fp8b1(sv), bf2f((unsigned short)(av >> 16)));
    if (blockIdx.x * 8 + wid * 2 + half < n) {
        int o = __builtin_amdgcn_cvt_pk_fp8_f32(di * z0, di * z1, 0, false);
        *reinterpret_cast<unsigned short*>(uout + (size_t)r * 64 + fl * 2) =
            (unsigned short)(o & 0xFFFF);
    }
}

// final step fused with log_softmax, writes f32 out
__global__ void k_prop_lsm(const unsigned char* __restrict__ uin, const unsigned short* __restrict__ ah,
                           const float* __restrict__ dinv, const int* __restrict__ row_ptr,
                           const int* __restrict__ cols, float* __restrict__ out, int n) {
    int wid = threadIdx.x >> 6;
    int lane = threadIdx.x & 63;
    int half = lane >> 5, fl = lane & 31;
    int r0 = blockIdx.x * 8 + wid * 2;
    int ra = min(r0, n - 1), rb = min(r0 + 1, n - 1);
    int ea = row_ptr[ra], enda = row_ptr[ra + 1];
    int eb = row_ptr[rb], endb = row_ptr[rb + 1];
    int trips = (max(enda - ea, endb - eb) + 7) >> 3;
    int e0 = half ? eb : ea;
    int end_ = half ? endb : enda;
    int r = half ? rb : ra;

    float s0 = 0.f, s1 = 0.f, s2 = 0.f, s3 = 0.f, s4 = 0.f, s5 = 0.f, s6 = 0.f, s7 = 0.f;
    float t0 = 0.f, t1 = 0.f, t2 = 0.f, t3 = 0.f, t4 = 0.f, t5 = 0.f, t6 = 0.f, t7 = 0.f;
    for (int t = 0; t < trips; ++t) {
        int base = e0 + t * 8;
        int q0 = cols[base],     q1 = cols[base + 1], q2 = cols[base + 2], q3 = cols[base + 3];
        int q4 = cols[base + 4], q5 = cols[base + 5], q6 = cols[base + 6], q7 = cols[base + 7];
        int c0 = (base     < end_) ? q0 : n;
        int c1 = (base + 1 < end_) ? q1 : n;
        int c2 = (base + 2 < end_) ? q2 : n;
        int c3 = (base + 3 < end_) ? q3 : n;
        int c4 = (base + 4 < end_) ? q4 : n;
        int c5 = (base + 5 < end_) ? q5 : n;
        int c6 = (base + 6 < end_) ? q6 : n;
        int c7 = (base + 7 < end_) ? q7 : n;
        unsigned v0 = *reinterpret_cast<const unsigned short*>(uin + (size_t)c0 * 64 + fl * 2);
        unsigned v1 = *reinterpret_cast<const unsigned short*>(uin + (size_t)c1 * 64 + fl * 2);
        unsigned v2 = *reinterpret_cast<const unsigned short*>(uin + (size_t)c2 * 64 + fl * 2);
        unsigned v3 = *reinterpret_cast<const unsigned short*>(uin + (size_t)c3 * 64 + fl * 2);
        unsigned v4 = *reinterpret_cast<const unsigned short*>(uin + (size_t)c4 * 64 + fl * 2);
        unsigned v5 = *reinterpret_cast<const unsigned short*>(uin + (size_t)c5 * 64 + fl * 2);
        unsigned v6 = *reinterpret_cast<const unsigned short*>(uin + (size_t)c6 * 64 + fl * 2);
        unsigned v7 = *reinterpret_cast<const unsigned short*>(uin + (size_t)c7 * 64 + fl * 2);
        s0 += fp8b0(v0); t0 += fp8b1(v0);
        s1 += fp8b0(v1); t1 += fp8b1(v1);
        s2 += fp8b0(v2); t2 += fp8b1(v2);
        s3 += fp8b0(v3); t3 += fp8b1(v3);
        s4 += fp8b0(v4); t4 += fp8b1(v4);
        s5 += fp8b0(v5); t5 += fp8b1(v5);
        s6 += fp8b0(v6); t6 += fp8b1(v6);
        s7 += fp8b0(v7); t7 += fp8b1(v7);
    }
    float sa = ((s0 + s1) + (s2 + s3)) + ((s4 + s5) + (s6 + s7));
    float sb = ((t0 + t1) + (t2 + t3)) + ((t4 + t5) + (t6 + t7));
    unsigned sv = *reinterpret_cast<const unsigned short*>(uin + (size_t)r * 64 + fl * 2);
    unsigned av = *reinterpret_cast<const unsigned*>(ah + (size_t)r * 64 + fl * 2);
    float di = dinv[r];
    float w = 0.9f * di;
    float z0 = fmaf(w, sa + fp8b0(sv), bf2f((unsigned short)(av & 0xFFFF)));
    float z1 = fmaf(w, sb + fp8b1(sv), bf2f((unsigned short)(av >> 16)));
    // softmax across the 32 feature-lanes of this half-wave (offsets <32 keep halves apart)
    float m = fmaxf(z0, z1);
#pragma unroll
    for (int o = 1; o <= 16; o <<= 1) m = fmaxf(m, __shfl_xor(m, o, 64));
    float s = expf(z0 - m) + expf(z1 - m);
#pragma unroll
    for (int o = 1; o <= 16; o <<= 1) s += __shfl_xor(s, o, 64);
    float ls = m + logf(s);
    if (blockIdx.x * 8 + wid * 2 + half < n) {
        float2 o2 = make_float2(z0 - ls, z1 - ls);
        *reinterpret_cast<float2*>(out + (size_t)r * 64 + fl * 2) = o2;
    }
}

// ---------------- launch ----------------
extern "C" void kernel_launch(void* const* d_in, const int* in_sizes, int n_in,
                              void* d_out, int out_size, void* d_ws, size_t ws_size,
                              hipStream_t stream) {
    const float* x  = (const float*)d_in[0];
    const float* w1 = (const float*)d_in[1];
    const float* b1 = (const float*)d_in[2];
    const float* w2 = (const float*)d_in[3];
    const float* b2 = (const float*)d_in[4];
    const int*   ei = (const int*)d_in[5];
    // d_in[6] = K (always 10; launch count must be graph-static)

    int F = in_sizes[1] / 64;         // 1024
    int N = in_sizes[0] / F;          // 100000
    int E = in_sizes[5] / 2;          // 3200000
    int NB = (N + 255) >> 8;          // 391 buckets

    char* p = (char*)d_ws;
    auto alloc = [&](size_t bytes) {
        void* r = (void*)p;
        p += (bytes + 255) & ~(size_t)255;
        return r;
    };
    unsigned short* ah   = (unsigned short*)alloc((size_t)N * 64 * 2);
    unsigned char*  u0   = (unsigned char*)alloc((size_t)(N + 1) * 64);
    unsigned char*  uA   = (unsigned char*)alloc((size_t)(N + 1) * 64);
    unsigned char*  uB   = (unsigned char*)alloc((size_t)(N + 1) * 64);
    float* dinv    = (float*)alloc((size_t)N * 4);
    int*   row_ptr = (int*)alloc((size_t)(N + 1) * 4);
    int*   btot    = (int*)alloc(2048);
    int*   bstart  = (int*)alloc(2048);
    int*   bcur    = (int*)alloc(2048);
    unsigned* ebuf = (unsigned*)alloc((size_t)E * 4);
    int*   cols    = (int*)alloc((size_t)(E + 256) * 4);  // pad: unconditional 8-wide loads
    short* w1f     = (short*)alloc((size_t)F * 64 * 2);
    short* w2f     = (short*)alloc((size_t)64 * 64 * 2);

    int neb = (E + 4095) / 4096;

    k_zero<<<2, 256, 0, stream>>>(btot, NB);
    k_hist<<<neb, 256, 0, stream>>>(ei, btot, E, NB);
    k_scanb<<<1, 512, 0, stream>>>(btot, bstart, bcur, row_ptr, NB, N, E);
    k_part<<<neb, 256, 0, stream>>>(ei, bcur, ebuf, E, NB);
    k_bucket<<<NB, 256, 0, stream>>>(ebuf, bstart, row_ptr, dinv, cols, N);
    k_zrow<<<1, 64, 0, stream>>>(u0, uA, uB, N);
    k_pack_w1<<<(F * 64) / 256, 256, 0, stream>>>(w1, w1f);
    k_pack_w2<<<16, 256, 0, stream>>>(w2, w2f);
    k_mlp<<<(N + 63) / 64, 256, 0, stream>>>(x, (const short8*)w1f, b1,
                                             (const short8*)w2f, b2,
                                             dinv, ah, u0, N, F);

    const unsigned char* uin = u0;
    unsigned char* bufs[2] = {uA, uB};
    int npb = (N + 7) / 8;  // 8 rows per block (4 waves x 2 rows)
    for (int k = 0; k < KSTEPS - 1; ++k) {
        unsigned char* uo = bufs[k & 1];
        k_prop<<<npb, 256, 0, stream>>>(uin, ah, dinv, row_ptr, cols, uo, N);
        uin = uo;
    }
    k_prop_lsm<<<npb, 256, 0, stream>>>(uin, ah, dinv, row_ptr, cols, (float*)d_out, N);
}

// Round 12
// 675.884 us; speedup vs baseline: 1.2799x; 1.0041x over previous
//
#include <hip/hip_runtime.h>
#include <math.h>

// APPNP: h = relu(x@W1+b1)@W2+b2 ; z_{k+1} = 0.9*Ahat z_k + 0.1*h (10 steps); log_softmax
// Ahat = D^-1/2 (A + I) D^-1/2.
// u-space propagation: u = D^-1/2 z -> (Ahat z)_i = dinv_i * (sum_{j in N(i)} u_j + u_i).
// CSR via bucketed counting sort (8192 edges/block). MLP via bf16 MFMA, 2 m-tiles per
// wave (B-frags shared). u in fp8 e4m3; ah=0.1*h bf16. Prop v3: two adjacent rows per
// wave (32 lanes x 2 fp8 feats), 8-deep unroll, padded cols -> unconditional loads.

constexpr int KSTEPS = 10;

typedef __attribute__((ext_vector_type(8))) short short8;
typedef __attribute__((ext_vector_type(4))) float f32x4;

static __device__ __forceinline__ unsigned short f2bf(float f) {
    unsigned u = __builtin_bit_cast(unsigned, f);
    unsigned r = (u + 0x7FFFu + ((u >> 16) & 1u)) >> 16;
    return (unsigned short)r;
}
static __device__ __forceinline__ float bf2f(unsigned short b) {
    unsigned u = (unsigned)b << 16;
    return __builtin_bit_cast(float, u);
}
static __device__ __forceinline__ unsigned char f2fp8(float f) {
    int p = __builtin_amdgcn_cvt_pk_fp8_f32(f, f, 0, false);
    return (unsigned char)(p & 0xFF);
}
static __device__ __forceinline__ float fp8b0(unsigned v) {
    return __builtin_amdgcn_cvt_f32_fp8((int)v, 0);
}
static __device__ __forceinline__ float fp8b1(unsigned v) {
    return __builtin_amdgcn_cvt_f32_fp8((int)v, 1);
}

// ---------------- bucketed CSR build ----------------
// bucket = row >> 8 (256 rows per bucket); NB = ceil(N/256) buckets

__global__ void k_zero(int* __restrict__ p, int n) {
    int i = blockIdx.x * 256 + threadIdx.x;
    if (i < n) p[i] = 0;
}

__global__ void k_hist(const int* __restrict__ ei, int* __restrict__ btot, int E, int NB) {
    __shared__ int hist[512];
    for (int t = threadIdx.x; t < NB; t += 256) hist[t] = 0;
    __syncthreads();
    int base = blockIdx.x * 8192;
#pragma unroll
    for (int k = 0; k < 32; ++k) {
        int e = base + k * 256 + threadIdx.x;
        if (e < E) atomicAdd(&hist[ei[e] >> 8], 1);
    }
    __syncthreads();
    for (int t = threadIdx.x; t < NB; t += 256) {
        int c = hist[t];
        if (c) atomicAdd(&btot[t], c);
    }
}

__global__ void k_scanb(const int* __restrict__ btot, int* __restrict__ bstart,
                        int* __restrict__ bcur, int* __restrict__ row_ptr,
                        int NB, int N, int E) {
    __shared__ int lds[512];
    int t = threadIdx.x;
    int v0 = (t < NB) ? btot[t] : 0;
    int v = v0;
    lds[t] = v;
    __syncthreads();
    for (int o = 1; o < 512; o <<= 1) {
        int a = (t >= o) ? lds[t - o] : 0;
        __syncthreads();
        v += a;
        lds[t] = v;
        __syncthreads();
    }
    if (t < NB) {
        int ex = v - v0;
        bstart[t] = ex;
        bcur[t] = ex;
    }
    if (t == 0) {
        bstart[NB] = E;
        row_ptr[N] = E;
    }
}

// partition edges into bucket slices; entry packed as col | (row&255)<<24 (col < 2^17)
__launch_bounds__(256)
__global__ void k_part(const int* __restrict__ ei, int* __restrict__ bcur,
                       unsigned* __restrict__ ebuf, int E, int NB) {
    __shared__ int hist[512], rebase[512], lcur[512];
    for (int t = threadIdx.x; t < NB; t += 256) { hist[t] = 0; lcur[t] = 0; }
    __syncthreads();
    int base = blockIdx.x * 8192;
    int r[32], c[32];
#pragma unroll
    for (int k = 0; k < 32; ++k) {
        int e = base + k * 256 + threadIdx.x;
        bool ok = e < E;
        r[k] = ok ? ei[e] : -1;
        c[k] = ok ? ei[E + e] : 0;
        if (ok) atomicAdd(&hist[r[k] >> 8], 1);
    }
    __syncthreads();
    for (int t = threadIdx.x; t < NB; t += 256) {
        int cnt = hist[t];
        rebase[t] = cnt ? atomicAdd(&bcur[t], cnt) : 0;
    }
    __syncthreads();
#pragma unroll
    for (int k = 0; k < 32; ++k) {
        if (r[k] >= 0) {
            int b = r[k] >> 8;
            int pos = rebase[b] + atomicAdd(&lcur[b], 1);
            ebuf[pos] = (unsigned)c[k] | ((unsigned)(r[k] & 255) << 24);
        }
    }
}

__launch_bounds__(256)
__global__ void k_bucket(const unsigned* __restrict__ ebuf, const int* __restrict__ bstart,
                         int* __restrict__ row_ptr, float* __restrict__ dinv,
                         int* __restrict__ cols, int N) {
    __shared__ int cnt[256], cur[256], lds[256];
    int b = blockIdx.x, t = threadIdx.x;
    int s = bstart[b], e2 = bstart[b + 1];
    cnt[t] = 0;
    __syncthreads();
    for (int i = s + t; i < e2; i += 256) {
        unsigned p = ebuf[i];
        atomicAdd(&cnt[p >> 24], 1);
    }
    __syncthreads();
    int v0 = cnt[t];
    int v = v0;
    lds[t] = v;
    __syncthreads();
    for (int o = 1; o < 256; o <<= 1) {
        int a = (t >= o) ? lds[t - o] : 0;
        __syncthreads();
        v += a;
        lds[t] = v;
        __syncthreads();
    }
    int excl = v - v0;
    int row = (b << 8) + t;
    if (row < N) {
        row_ptr[row] = s + excl;
        dinv[row] = rsqrtf((float)(v0 + 1));
    }
    cur[t] = s + excl;
    __syncthreads();
    for (int i = s + t; i < e2; i += 256) {
        unsigned p = ebuf[i];
        int pos = atomicAdd(&cur[p >> 24], 1);
        cols[pos] = (int)(p & 0x00FFFFFFu);
    }
}

// zero-pad row N of the u buffers (predicated tail gathers land here)
__global__ void k_zrow(unsigned char* __restrict__ a, unsigned char* __restrict__ b,
                       unsigned char* __restrict__ c, int N) {
    int t = threadIdx.x;  // 64
    size_t o = (size_t)N * 64 + t;
    a[o] = 0; b[o] = 0; c[o] = 0;
}

// ---------------- weight packing into MFMA fragment order ----------------
__global__ void k_pack_w1(const float* __restrict__ w1, short* __restrict__ w1f) {
    int t = blockIdx.x * 256 + threadIdx.x;  // 65536 total
    int j = t & 7, lane = (t >> 3) & 63, nb = (t >> 9) & 3, kb = t >> 11;
    int k = kb * 32 + ((lane >> 4) << 3) + j;
    int c = nb * 16 + (lane & 15);
    w1f[t] = (short)f2bf(w1[k * 64 + c]);
}

__global__ void k_pack_w2(const float* __restrict__ w2, short* __restrict__ w2f) {
    int t = blockIdx.x * 256 + threadIdx.x;  // 4096 total
    int j = t & 7, lane = (t >> 3) & 63, nb = (t >> 9) & 3, kb = (t >> 11) & 1;
    int k = kb * 32 + ((lane >> 4) << 3) + j;
    int c = nb * 16 + (lane & 15);
    w2f[t] = (short)f2bf(w2[k * 64 + c]);
}

// ---------------- fused 2-layer MLP via bf16 MFMA, 2 m-tiles per wave ----------------
// block = 256 threads = 4 waves; wave w owns tiles w and w+4 (16 rows each) -> 128 rows
// per block; B-fragments loaded once per kk serve both tiles.
__launch_bounds__(256)
__global__ void k_mlp(const float* __restrict__ x, const short8* __restrict__ w1f,
                      const float* __restrict__ b1, const short8* __restrict__ w2f,
                      const float* __restrict__ b2, const float* __restrict__ dinv,
                      unsigned short* __restrict__ ah, unsigned char* __restrict__ u0,
                      int M, int F) {
    __shared__ __align__(16) short c1s[8][16][64];  // 16 KB
    int tid = threadIdx.x;
    int w = tid >> 6, lane = tid & 63;
    int hi = lane >> 4, lx = lane & 15;
    int rb0 = blockIdx.x * 128 + w * 16;
    int rb1 = rb0 + 64;
    int row0 = rb0 + lx, row1 = rb1 + lx;
    size_t rc0 = (row0 < M) ? (size_t)row0 : (size_t)(M - 1);
    size_t rc1 = (row1 < M) ? (size_t)row1 : (size_t)(M - 1);
    const float* xr0 = x + rc0 * (size_t)F + hi * 8;
    const float* xr1 = x + rc1 * (size_t)F + hi * 8;

    f32x4 acc0[4], acc1[4];
#pragma unroll
    for (int nb = 0; nb < 4; ++nb) {
        acc0[nb] = (f32x4){0.f, 0.f, 0.f, 0.f};
        acc1[nb] = (f32x4){0.f, 0.f, 0.f, 0.f};
    }

    int KK = F >> 5;
#pragma unroll 2
    for (int kk = 0; kk < KK; ++kk) {
        float4 p0 = *reinterpret_cast<const float4*>(xr0 + kk * 32);
        float4 p1 = *reinterpret_cast<const float4*>(xr0 + kk * 32 + 4);
        float4 q0 = *reinterpret_cast<const float4*>(xr1 + kk * 32);
        float4 q1 = *reinterpret_cast<const float4*>(xr1 + kk * 32 + 4);
        short8 af0, af1;
        af0[0] = (short)f2bf(p0.x); af0[1] = (short)f2bf(p0.y);
        af0[2] = (short)f2bf(p0.z); af0[3] = (short)f2bf(p0.w);
        af0[4] = (short)f2bf(p1.x); af0[5] = (short)f2bf(p1.y);
        af0[6] = (short)f2bf(p1.z); af0[7] = (short)f2bf(p1.w);
        af1[0] = (short)f2bf(q0.x); af1[1] = (short)f2bf(q0.y);
        af1[2] = (short)f2bf(q0.z); af1[3] = (short)f2bf(q0.w);
        af1[4] = (short)f2bf(q1.x); af1[5] = (short)f2bf(q1.y);
        af1[6] = (short)f2bf(q1.z); af1[7] = (short)f2bf(q1.w);
#pragma unroll
        for (int nb = 0; nb < 4; ++nb) {
            short8 bf = w1f[(kk * 4 + nb) * 64 + lane];
            acc0[nb] = __builtin_amdgcn_mfma_f32_16x16x32_bf16(af0, bf, acc0[nb], 0, 0, 0);
            acc1[nb] = __builtin_amdgcn_mfma_f32_16x16x32_bf16(af1, bf, acc1[nb], 0, 0, 0);
        }
    }

    // bias + relu -> LDS (tiles w and w+4)
#pragma unroll
    for (int nb = 0; nb < 4; ++nb) {
        int col = nb * 16 + lx;
        float bb = b1[col];
#pragma unroll
        for (int r = 0; r < 4; ++r) {
            int rr = hi * 4 + r;
            c1s[w][rr][col]     = (short)f2bf(fmaxf(acc0[nb][r] + bb, 0.f));
            c1s[w + 4][rr][col] = (short)f2bf(fmaxf(acc1[nb][r] + bb, 0.f));
        }
    }
    __syncthreads();

    f32x4 acc20[4], acc21[4];
#pragma unroll
    for (int nb = 0; nb < 4; ++nb) {
        acc20[nb] = (f32x4){0.f, 0.f, 0.f, 0.f};
        acc21[nb] = (f32x4){0.f, 0.f, 0.f, 0.f};
    }
#pragma unroll
    for (int kb = 0; kb < 2; ++kb) {
        short8 a20 = *reinterpret_cast<const short8*>(&c1s[w][lx][kb * 32 + hi * 8]);
        short8 a21 = *reinterpret_cast<const short8*>(&c1s[w + 4][lx][kb * 32 + hi * 8]);
#pragma unroll
        for (int nb = 0; nb < 4; ++nb) {
            short8 bf2 = w2f[(kb * 4 + nb) * 64 + lane];
            acc20[nb] = __builtin_amdgcn_mfma_f32_16x16x32_bf16(a20, bf2, acc20[nb], 0, 0, 0);
            acc21[nb] = __builtin_amdgcn_mfma_f32_16x16x32_bf16(a21, bf2, acc21[nb], 0, 0, 0);
        }
    }

#pragma unroll
    for (int r = 0; r < 4; ++r) {
        int o0 = rb0 + hi * 4 + r;
        int o1 = rb1 + hi * 4 + r;
        float dv0 = (o0 < M) ? dinv[o0] : 0.f;
        float dv1 = (o1 < M) ? dinv[o1] : 0.f;
#pragma unroll
        for (int nb = 0; nb < 4; ++nb) {
            int col = nb * 16 + lx;
            float bb = b2[col];
            if (o0 < M) {
                float v = acc20[nb][r] + bb;
                ah[(size_t)o0 * 64 + col] = f2bf(0.1f * v);
                u0[(size_t)o0 * 64 + col] = f2fp8(dv0 * v);
            }
            if (o1 < M) {
                float v = acc21[nb][r] + bb;
                ah[(size_t)o1 * 64 + col] = f2bf(0.1f * v);
                u0[(size_t)o1 * 64 + col] = f2fp8(dv1 * v);
            }
        }
    }
}

// ---------------- propagation v3: 2 adjacent rows per wave (fp8 u) ----------------
__global__ void k_prop(const unsigned char* __restrict__ uin, const unsigned short* __restrict__ ah,
                       const float* __restrict__ dinv, const int* __restrict__ row_ptr,
                       const int* __restrict__ cols, unsigned char* __restrict__ uout, int n) {
    int wid = threadIdx.x >> 6;
    int lane = threadIdx.x & 63;
    int half = lane >> 5, fl = lane & 31;
    int r0 = blockIdx.x * 8 + wid * 2;
    int ra = min(r0, n - 1), rb = min(r0 + 1, n - 1);
    int ea = row_ptr[ra], enda = row_ptr[ra + 1];
    int eb = row_ptr[rb], endb = row_ptr[rb + 1];
    int trips = (max(enda - ea, endb - eb) + 7) >> 3;
    int e0 = half ? eb : ea;
    int end_ = half ? endb : enda;
    int r = half ? rb : ra;

    float s0 = 0.f, s1 = 0.f, s2 = 0.f, s3 = 0.f, s4 = 0.f, s5 = 0.f, s6 = 0.f, s7 = 0.f;
    float t0 = 0.f, t1 = 0.f, t2 = 0.f, t3 = 0.f, t4 = 0.f, t5 = 0.f, t6 = 0.f, t7 = 0.f;
    for (int t = 0; t < trips; ++t) {
        int base = e0 + t * 8;
        int q0 = cols[base],     q1 = cols[base + 1], q2 = cols[base + 2], q3 = cols[base + 3];
        int q4 = cols[base + 4], q5 = cols[base + 5], q6 = cols[base + 6], q7 = cols[base + 7];
        int c0 = (base     < end_) ? q0 : n;
        int c1 = (base + 1 < end_) ? q1 : n;
        int c2 = (base + 2 < end_) ? q2 : n;
        int c3 = (base + 3 < end_) ? q3 : n;
        int c4 = (base + 4 < end_) ? q4 : n;
        int c5 = (base + 5 < end_) ? q5 : n;
        int c6 = (base + 6 < end_) ? q6 : n;
        int c7 = (base + 7 < end_) ? q7 : n;
        unsigned v0 = *reinterpret_cast<const unsigned short*>(uin + (size_t)c0 * 64 + fl * 2);
        unsigned v1 = *reinterpret_cast<const unsigned short*>(uin + (size_t)c1 * 64 + fl * 2);
        unsigned v2 = *reinterpret_cast<const unsigned short*>(uin + (size_t)c2 * 64 + fl * 2);
        unsigned v3 = *reinterpret_cast<const unsigned short*>(uin + (size_t)c3 * 64 + fl * 2);
        unsigned v4 = *reinterpret_cast<const unsigned short*>(uin + (size_t)c4 * 64 + fl * 2);
        unsigned v5 = *reinterpret_cast<const unsigned short*>(uin + (size_t)c5 * 64 + fl * 2);
        unsigned v6 = *reinterpret_cast<const unsigned short*>(uin + (size_t)c6 * 64 + fl * 2);
        unsigned v7 = *reinterpret_cast<const unsigned short*>(uin + (size_t)c7 * 64 + fl * 2);
        s0 += fp8b0(v0); t0 += fp8b1(v0);
        s1 += fp8b0(v1); t1 += fp8b1(v1);
        s2 += fp8b0(v2); t2 += fp8b1(v2);
        s3 += fp8b0(v3); t3 += fp8b1(v3);
        s4 += fp8b0(v4); t4 += fp8b1(v4);
        s5 += fp8b0(v5); t5 += fp8b1(v5);
        s6 += fp8b0(v6); t6 += fp8b1(v6);
        s7 += fp8b0(v7); t7 += fp8b1(v7);
    }
    float sa = ((s0 + s1) + (s2 + s3)) + ((s4 + s5) + (s6 + s7));
    float sb = ((t0 + t1) + (t2 + t3)) + ((t4 + t5) + (t6 + t7));
    unsigned sv = *reinterpret_cast<const unsigned short*>(uin + (size_t)r * 64 + fl * 2);
    unsigned av = *reinterpret_cast<const unsigned*>(ah + (size_t)r * 64 + fl * 2);
    float di = dinv[r];
    float w = 0.9f * di;
    float z0 = fmaf(w, sa + fp8b0(sv), bf2f((unsigned short)(av & 0xFFFF)));
    float z1 = fmaf(w, sb + fp8b1(sv), bf2f((unsigned short)(av >> 16)));
    if (blockIdx.x * 8 + wid * 2 + half < n) {
        int o = __builtin_amdgcn_cvt_pk_fp8_f32(di * z0, di * z1, 0, false);
        *reinterpret_cast<unsigned short*>(uout + (size_t)r * 64 + fl * 2) =
            (unsigned short)(o & 0xFFFF);
    }
}

// final step fused with log_softmax, writes f32 out
__global__ void k_prop_lsm(const unsigned char* __restrict__ uin, const unsigned short* __restrict__ ah,
                           const float* __restrict__ dinv, const int* __restrict__ row_ptr,
                           const int* __restrict__ cols, float* __restrict__ out, int n) {
    int wid = threadIdx.x >> 6;
    int lane = threadIdx.x & 63;
    int half = lane >> 5, fl = lane & 31;
    int r0 = blockIdx.x * 8 + wid * 2;
    int ra = min(r0, n - 1), rb = min(r0 + 1, n - 1);
    int ea = row_ptr[ra], enda = row_ptr[ra + 1];
    int eb = row_ptr[rb], endb = row_ptr[rb + 1];
    int trips = (max(enda - ea, endb - eb) + 7) >> 3;
    int e0 = half ? eb : ea;
    int end_ = half ? endb : enda;
    int r = half ? rb : ra;

    float s0 = 0.f, s1 = 0.f, s2 = 0.f, s3 = 0.f, s4 = 0.f, s5 = 0.f, s6 = 0.f, s7 = 0.f;
    float t0 = 0.f, t1 = 0.f, t2 = 0.f, t3 = 0.f, t4 = 0.f, t5 = 0.f, t6 = 0.f, t7 = 0.f;
    for (int t = 0; t < trips; ++t) {
        int base = e0 + t * 8;
        int q0 = cols[base],     q1 = cols[base + 1], q2 = cols[base + 2], q3 = cols[base + 3];
        int q4 = cols[base + 4], q5 = cols[base + 5], q6 = cols[base + 6], q7 = cols[base + 7];
        int c0 = (base     < end_) ? q0 : n;
        int c1 = (base + 1 < end_) ? q1 : n;
        int c2 = (base + 2 < end_) ? q2 : n;
        int c3 = (base + 3 < end_) ? q3 : n;
        int c4 = (base + 4 < end_) ? q4 : n;
        int c5 = (base + 5 < end_) ? q5 : n;
        int c6 = (base + 6 < end_) ? q6 : n;
        int c7 = (base + 7 < end_) ? q7 : n;
        unsigned v0 = *reinterpret_cast<const unsigned short*>(uin + (size_t)c0 * 64 + fl * 2);
        unsigned v1 = *reinterpret_cast<const unsigned short*>(uin + (size_t)c1 * 64 + fl * 2);
        unsigned v2 = *reinterpret_cast<const unsigned short*>(uin + (size_t)c2 * 64 + fl * 2);
        unsigned v3 = *reinterpret_cast<const unsigned short*>(uin + (size_t)c3 * 64 + fl * 2);
        unsigned v4 = *reinterpret_cast<const unsigned short*>(uin + (size_t)c4 * 64 + fl * 2);
        unsigned v5 = *reinterpret_cast<const unsigned short*>(uin + (size_t)c5 * 64 + fl * 2);
        unsigned v6 = *reinterpret_cast<const unsigned short*>(uin + (size_t)c6 * 64 + fl * 2);
        unsigned v7 = *reinterpret_cast<const unsigned short*>(uin + (size_t)c7 * 64 + fl * 2);
        s0 += fp8b0(v0); t0 += fp8b1(v0);
        s1 += fp8b0(v1); t1 += fp8b1(v1);
        s2 += fp8b0(v2); t2 += fp8b1(v2);
        s3 += fp8b0(v3); t3 += fp8b1(v3);
        s4 += fp8b0(v4); t4 += fp8b1(v4);
        s5 += fp8b0(v5); t5 += fp8b1(v5);
        s6 += fp8b0(v6); t6 += fp8b1(v6);
        s7 += fp8b0(v7); t7 += fp8b1(v7);
    }
    float sa = ((s0 + s1) + (s2 + s3)) + ((s4 + s5) + (s6 + s7));
    float sb = ((t0 + t1) + (t2 + t3)) + ((t4 + t5) + (t6 + t7));
    unsigned sv = *reinterpret_cast<const unsigned short*>(uin + (size_t)r * 64 + fl * 2);
    unsigned av = *reinterpret_cast<const unsigned*>(ah + (size_t)r * 64 + fl * 2);
    float di = dinv[r];
    float w = 0.9f * di;
    float z0 = fmaf(w, sa + fp8b0(sv), bf2f((unsigned short)(av & 0xFFFF)));
    float z1 = fmaf(w, sb + fp8b1(sv), bf2f((unsigned short)(av >> 16)));
    float m = fmaxf(z0, z1);
#pragma unroll
    for (int o = 1; o <= 16; o <<= 1) m = fmaxf(m, __shfl_xor(m, o, 64));
    float s = expf(z0 - m) + expf(z1 - m);
#pragma unroll
    for (int o = 1; o <= 16; o <<= 1) s += __shfl_xor(s, o, 64);
    float ls = m + logf(s);
    if (blockIdx.x * 8 + wid * 2 + half < n) {
        float2 o2 = make_float2(z0 - ls, z1 - ls);
        *reinterpret_cast<float2*>(out + (size_t)r * 64 + fl * 2) = o2;
    }
}

// ---------------- launch ----------------
extern "C" void kernel_launch(void* const* d_in, const int* in_sizes, int n_in,
                              void* d_out, int out_size, void* d_ws, size_t ws_size,
                              hipStream_t stream) {
    const float* x  = (const float*)d_in[0];
    const float* w1 = (const float*)d_in[1];
    const float* b1 = (const float*)d_in[2];
    const float* w2 = (const float*)d_in[3];
    const float* b2 = (const float*)d_in[4];
    const int*   ei = (const int*)d_in[5];
    // d_in[6] = K (always 10; launch count must be graph-static)

    int F = in_sizes[1] / 64;         // 1024
    int N = in_sizes[0] / F;          // 100000
    int E = in_sizes[5] / 2;          // 3200000
    int NB = (N + 255) >> 8;          // 391 buckets

    char* p = (char*)d_ws;
    auto alloc = [&](size_t bytes) {
        void* r = (void*)p;
        p += (bytes + 255) & ~(size_t)255;
        return r;
    };
    unsigned short* ah   = (unsigned short*)alloc((size_t)N * 64 * 2);
    unsigned char*  u0   = (unsigned char*)alloc((size_t)(N + 1) * 64);
    unsigned char*  uA   = (unsigned char*)alloc((size_t)(N + 1) * 64);
    unsigned char*  uB   = (unsigned char*)alloc((size_t)(N + 1) * 64);
    float* dinv    = (float*)alloc((size_t)N * 4);
    int*   row_ptr = (int*)alloc((size_t)(N + 1) * 4);
    int*   btot    = (int*)alloc(2048);
    int*   bstart  = (int*)alloc(2048);
    int*   bcur    = (int*)alloc(2048);
    unsigned* ebuf = (unsigned*)alloc((size_t)E * 4);
    int*   cols    = (int*)alloc((size_t)(E + 256) * 4);  // pad: unconditional 8-wide loads
    short* w1f     = (short*)alloc((size_t)F * 64 * 2);
    short* w2f     = (short*)alloc((size_t)64 * 64 * 2);

    int neb = (E + 8191) / 8192;

    k_zero<<<2, 256, 0, stream>>>(btot, NB);
    k_hist<<<neb, 256, 0, stream>>>(ei, btot, E, NB);
    k_scanb<<<1, 512, 0, stream>>>(btot, bstart, bcur, row_ptr, NB, N, E);
    k_part<<<neb, 256, 0, stream>>>(ei, bcur, ebuf, E, NB);
    k_bucket<<<NB, 256, 0, stream>>>(ebuf, bstart, row_ptr, dinv, cols, N);
    k_zrow<<<1, 64, 0, stream>>>(u0, uA, uB, N);
    k_pack_w1<<<(F * 64) / 256, 256, 0, stream>>>(w1, w1f);
    k_pack_w2<<<16, 256, 0, stream>>>(w2, w2f);
    k_mlp<<<(N + 127) / 128, 256, 0, stream>>>(x, (const short8*)w1f, b1,
                                               (const short8*)w2f, b2,
                                               dinv, ah, u0, N, F);

    const unsigned char* uin = u0;
    unsigned char* bufs[2] = {uA, uB};
    int npb = (N + 7) / 8;  // 8 rows per block (4 waves x 2 rows)
    for (int k = 0; k < KSTEPS - 1; ++k) {
        unsigned char* uo = bufs[k & 1];
        k_prop<<<npb, 256, 0, stream>>>(uin, ah, dinv, row_ptr, cols, uo, N);
        uin = uo;
    }
    k_prop_lsm<<<npb, 256, 0, stream>>>(uin, ah, dinv, row_ptr, cols, (float*)d_out, N);
}